// Round 10
// baseline (596.637 us; speedup 1.0000x reference)
//
#include <hip/hip_runtime.h>

// LSTMTrafficPredictor: fused 2-layer LSTM + FC head via MFMA.
// B=2048, T=512, IN=4, H1=64, H2=32, FC=16, OUT=1.
//
// R27 = R26 resubmitted byte-for-byte: Round-9 bench died with
// "MI355X container failed twice" (broker/infra; kernel never ran - same
// signature as Round 5, which re-ran cleanly). Audited for container-
// killers: no conditional barriers (no deadlock), all LDS/global indices
// bounded, ~135 unified regs < 170 cap at bounds(384,3), graph-capture
// safe. Resubmitting unchanged to keep the A/B chain vs R25 (261us).
//
// R26: TWO INDEPENDENT RECURRENCES PER CU. grid=512, MB=4, BLK=384
// (6 waves: 4 L1 + 2 L2), 2 blocks co-resident per CU.
// R25 post-mortem: x-prefetch flat (-1%) -> x was L2-resident. Model at
// 261us (610cy/body): trans issue 384cy/SIMD/body == measured VALUBusy
// (60%); ~40% of cycles are serial-chain latency (read->MFMA x3 ->
// exchange -> 2-stage trans -> store -> barrier ~ 400cy) that 3 waves/SIMD
// can't cover BECAUSE all 12 waves share one barrier phase. R26 breaks the
// barrier domain: two blocks, each its own recurrence -> block B issues
// into block A's bubbles. Per CU per step-pair: trans unchanged (12 waves
// x 8, jobs stay lane-dense: 16 units x 4 batches = 64 jobs/wave), MFMA
// doubles (~300cy/SIMD, separate pipe), LDS pipe ~90% (main risk).
// Gate exchange: per-wave gsc publish (4x b128 write by cols<4 lanes + 1x
// b128 read) replaces xor-8 swizzle (cheaper issue; latency cheap now).
// CLOSED AXES (measured): issue-trimming (R19 flat), VALU x-fold (R20 -6%),
// dup-column stores (R22 -3%), MFMA chain-split (R24 -16%), x-prefetch
// depth (R25 flat), 1-block/CU variants of multi-block (old R10/R15 spill
// - that was the 8-wave pre-split structure; this design halves per-block
// waves so CU totals match).
// k-map (K=128): [h1(0..63) | x(64..67) | 0(68..95) | h2(96..127)]
//   L1 wave w<4: 4 tiles nt, unit w*16+nt*4+quad, ks {0,1,2}, C-init=bbU
//   L2 wave w>=4: 4 tiles nt, unit (w-4)*16+nt*4+quad, ks {0,1,3}
//   z offset(k,n) = (k>>5)*512 + (((k>>3)&3)*16+n)*8 + (k&7); frag read = lane*8.
// Job map (both layers): lane(quad,col) -> unit base+(col>>2)*4+quad,
//   batch col&3; gates fetched via gsc slot ((col>>2)*4+quad)*4+(col&3),
//   published by cols<4 lanes (slot (nt*4+quad)*4+col).

#define T_LEN 512
#define IN_F  4
#define H1    64
#define H2    32
#define FCN   16
#define MB    4
#define BLK   384
#define NW1   4     // layer-1 waves; waves NW1..5 are layer-2

typedef __attribute__((ext_vector_type(8))) short s8b;  // 8 bf16 = 4 VGPR
typedef __attribute__((ext_vector_type(4))) float f4;   // MFMA acc
typedef __attribute__((ext_vector_type(4))) int   i4;   // 4 dwords (pin unit)

union S8U { s8b v; i4 d; unsigned short u[8]; };
union F4U { f4 v; i4 d; float f[4]; };

// Pin 4 consecutive regs into AGPRs; asm def kills rematerialization.
#define APIN4(x) asm volatile("" : "+a"((x).d))

#define MF(a, b, c) __builtin_amdgcn_mfma_f32_16x16x32_bf16((a), (b), (c), 0, 0, 0)
#define EX2(x) __builtin_amdgcn_exp2f(x)

#define L2E   1.4426950408889634f
#define L2E2  2.885390081777927f   // 2*log2(e)

__device__ __forceinline__ float rcp_(float x) { return __builtin_amdgcn_rcpf(x); }
// tanh(x) via exp2: 1 - 2/(2^(2x*log2e)+1)
__device__ __forceinline__ float tanh_(float x) {
    return 1.0f - 2.0f * rcp_(EX2(x * L2E2) + 1.0f);
}

__device__ __forceinline__ unsigned short bf16_rne(float f) {   // loader only
    unsigned u = __float_as_uint(f);
    u = u + 0x7FFFu + ((u >> 16) & 1u);
    return (unsigned short)(u >> 16);
}
__device__ __forceinline__ unsigned short bf16_cvt(float f) {   // hot path: 1 instr
    unsigned r;
    asm("v_cvt_pk_bf16_f32 %0, %1, %2" : "=v"(r) : "v"(f), "v"(f));
    return (unsigned short)r;
}

// Shared gate math (gates pre-scaled: i,f,o by log2e; g by 2*log2e).
#define GATES_MATH(G_, CREG, HOUT)                                              \
    const float dI = 1.0f + EX2(-(G_)[0]);                                      \
    const float dF = 1.0f + EX2(-(G_)[1]);                                      \
    const float rIF = rcp_(dI * dF);                                            \
    const float I = dF * rIF, F = dI * rIF;                                     \
    const float dG = EX2((G_)[2]) + 1.0f;                                       \
    const float dO = 1.0f + EX2(-(G_)[3]);                                      \
    const float rGO = rcp_(dG * dO);                                            \
    const float Gg = 1.0f - 2.0f * (dO * rGO), O = dG * rGO;                    \
    CREG = fmaf(F, CREG, I * Gg);                                               \
    const float HOUT = O * tanh_(CREG);

// 12 MFMA over 4 independent tile chains (depth 3), C-init = pinned bbU.
#define MFMA4(P, ZLAST)                                                         \
    f4 a0_, a1_, a2_, a3_;                                                      \
    {                                                                           \
        const s8b z0 = *(const s8b*)(&zz[P][0] + 0 * 512 + offF);               \
        const s8b z1 = *(const s8b*)(&zz[P][0] + 1 * 512 + offF);               \
        const s8b zL = *(const s8b*)(&zz[P][0] + (ZLAST) * 512 + offF);         \
        a0_ = MF(wfU[0][0].v, z0, bbU[0].v);                                    \
        a1_ = MF(wfU[1][0].v, z0, bbU[1].v);                                    \
        a2_ = MF(wfU[2][0].v, z0, bbU[2].v);                                    \
        a3_ = MF(wfU[3][0].v, z0, bbU[3].v);                                    \
        a0_ = MF(wfU[0][1].v, z1, a0_);                                         \
        a1_ = MF(wfU[1][1].v, z1, a1_);                                         \
        a2_ = MF(wfU[2][1].v, z1, a2_);                                         \
        a3_ = MF(wfU[3][1].v, z1, a3_);                                         \
        a0_ = MF(wfU[0][2].v, zL, a0_);                                         \
        a1_ = MF(wfU[1][2].v, zL, a1_);                                         \
        a2_ = MF(wfU[2][2].v, zL, a2_);                                         \
        a3_ = MF(wfU[3][2].v, zL, a3_);                                         \
    }

// Per-wave gsc exchange: cols<4 lanes publish 4 tiles; every lane reads its
// (unit,batch) job. Same-wave LDS -> no barrier, compiler inserts lgkmcnt.
#define GSC_XCHG(G_)                                                            \
    if (pubc) {                                                                 \
        *(f4*)&gsc[w][(0 * 4 + quad) * 4 + col][0] = a0_;                       \
        *(f4*)&gsc[w][(1 * 4 + quad) * 4 + col][0] = a1_;                       \
        *(f4*)&gsc[w][(2 * 4 + quad) * 4 + col][0] = a2_;                       \
        *(f4*)&gsc[w][(3 * 4 + quad) * 4 + col][0] = a3_;                       \
    }                                                                           \
    const f4 G_ = *(const f4*)&gsc[w][gslot][0];

__global__ __launch_bounds__(BLK, 3)
void lstm_mfma(const float* __restrict__ x,
               const float* __restrict__ Wih1, const float* __restrict__ Whh1,
               const float* __restrict__ bih1, const float* __restrict__ bhh1,
               const float* __restrict__ Wih2, const float* __restrict__ Whh2,
               const float* __restrict__ bih2, const float* __restrict__ bhh2,
               const float* __restrict__ fc1_w, const float* __restrict__ fc1_b,
               const float* __restrict__ fc2_w, const float* __restrict__ fc2_b,
               float* __restrict__ out)
{
    __shared__ __align__(16) unsigned short zz[2][2048];     // 8 KB
    __shared__ __align__(16) float gsc[6][64][4];            // 6 KB wave scratch
    __shared__ __align__(16) float h2f[MB * H2];
    __shared__ __align__(16) float fcs[MB * FCN];

    const int t    = threadIdx.x;
    const int lane = t & 63;
    const int w    = t >> 6;      // wave 0..5
    const int col  = lane & 15;
    const int quad = lane >> 4;
    const int b0   = blockIdx.x * MB;
    const int w2   = (w >= NW1) ? (w - NW1) : 0;   // L2 wave idx (clamped)
    const bool pubc = (col < MB);                  // publisher lanes
    const int b4   = col & 3;                      // job batch
    const int gslot = ((col >> 2) * 4 + quad) * 4 + b4;

    // ---- weight fragments (bf16, exp2-folded: g-gate rows x 2*log2e) ----
    // wfU/bbU are layer-1 data on waves 0..3, layer-2 data on waves 4..5.
    const float wsc = ((col & 3) == 2) ? L2E2 : L2E;
    S8U wfU[4][3];
    F4U bbU[4];
    if (w < NW1) {
        #pragma unroll
        for (int nt = 0; nt < 4; ++nt) {
            const int r1 = (col & 3) * 64 + w * 16 + nt * 4 + (col >> 2);
            #pragma unroll
            for (int ks = 0; ks < 3; ++ks) {
                #pragma unroll
                for (int j = 0; j < 8; ++j) {
                    const int k = ks * 32 + quad * 8 + j;
                    float wv = 0.f;
                    if      (k < H1)          wv = Whh1[r1 * H1 + k];
                    else if (k < H1 + IN_F)   wv = Wih1[r1 * IN_F + (k - H1)];
                    wfU[nt][ks].u[j] = bf16_rne(wv * wsc);
                }
            }
            #pragma unroll
            for (int j = 0; j < 4; ++j) {
                const float bsc = (j == 2) ? L2E2 : L2E;
                const int u = w * 16 + nt * 4 + quad;
                bbU[nt].f[j] = (bih1[j * 64 + u] + bhh1[j * 64 + u]) * bsc;
            }
        }
    } else {
        #pragma unroll
        for (int nt = 0; nt < 4; ++nt) {
            const int r2 = (col & 3) * 32 + w2 * 16 + nt * 4 + (col >> 2);
            #pragma unroll
            for (int kf = 0; kf < 3; ++kf) {
                #pragma unroll
                for (int j = 0; j < 8; ++j) {
                    const int k = ((kf < 2) ? kf * 32 : 96) + quad * 8 + j;
                    const float wv = (k < H1) ? Wih2[r2 * H1 + k]
                                              : Whh2[r2 * H2 + (k - 96)];
                    wfU[nt][kf].u[j] = bf16_rne(wv * wsc);
                }
            }
            #pragma unroll
            for (int j = 0; j < 4; ++j) {
                const float bsc = (j == 2) ? L2E2 : L2E;
                const int u = w2 * 16 + nt * 4 + quad;
                bbU[nt].f[j] = (bih2[j * 32 + u] + bhh2[j * 32 + u]) * bsc;
            }
        }
    }

    // ---- PIN fragments + biases into AGPRs (64 pins) ----
    #pragma unroll
    for (int nt = 0; nt < 4; ++nt) {
        #pragma unroll
        for (int ks = 0; ks < 3; ++ks) APIN4(wfU[nt][ks]);
        APIN4(bbU[nt]);
    }

    // ---- init LDS: zero z (both buffers) ----
    {
        int* pz = (int*)zz;       // 2*2048 shorts = 2048 ints
        for (int i = t; i < 2048; i += BLK) pz[i] = 0;
    }
    __syncthreads();
    if (t < MB * IN_F) {                    // x(0) at k=64+f: off = 1024 + n*8 + f
        const int n = t >> 2, f = t & 3;
        const float xv = x[(size_t)(b0 + n) * T_LEN * IN_F + f];
        zz[0][1024 + n * 8 + f] = bf16_rne(xv);
    }
    float c1 = 0.f;   // L1 job: unit w*16+(col>>2)*4+quad, batch col&3
    float c2 = 0.f;   // L2 job: unit w2*16+(col>>2)*4+quad, batch col&3

    // store offsets
    const int uH    = w * 16 + ((col >> 2) << 2) + quad;           // L1 (w<4)
    const int offH  = (uH >> 5) * 512 + (((uH >> 3) & 3) * 16 + b4) * 8 + (uH & 7);
    const int u2j   = w2 * 16 + ((col >> 2) << 2) + quad;          // L2 (w>=4)
    const int off2j = 1536 + (((u2j >> 3) & 3) * 16 + b4) * 8 + (u2j & 7);
    const int offF  = lane * 8;                    // frag read base
    const int xn_   = (t >> 2) & 3, xf_ = t & 3;   // x-prefetch role (t < 16)
    const int xoff  = 1024 + xn_ * 8 + xf_;
    const bool xr   = (t < MB * IN_F);
    const float* xp = x + (size_t)(b0 + xn_) * T_LEN * IN_F + IN_F + xf_;  // -> x(1)

    // x prefetch pipeline, depth 2 (R25): loads land >=2 bodies before store.
    float xv0 = 0.f, xv1 = 0.f;
    if (xr) {
        xv0 = xp[0];          // x(1)
        xv1 = xp[IN_F];       // x(2)
        xp += 2 * IN_F;       // -> x(3)
    }
    __syncthreads();

    // ================= main recurrence: unrolled x2, 1 barrier/body ==========
    #pragma unroll 1
    for (int s2 = 0; s2 < T_LEN / 2; ++s2) {
        // ---------- body A: s = 2*s2 (read zz[0], write zz[1]) ----------
        if (w < NW1) {
            float xnew = 0.f;
            if (xr && s2 < T_LEN / 2 - 1) xnew = xp[0];   // x(2*s2+3)
            MFMA4(0, 2)
            GSC_XCHG(g_)
            GATES_MATH(g_, c1, h_)
            zz[1][offH] = bf16_cvt(h_);
            if (xr) zz[1][xoff] = bf16_cvt(xv0);          // x(2*s2+1)
            xv0 = xv1; xv1 = xnew; xp += IN_F;
        } else {
            MFMA4(0, 3)
            if (s2 != 0) {                 // first body: h2(-1) must stay 0
                GSC_XCHG(g_)
                GATES_MATH(g_, c2, h_)
                zz[1][off2j] = bf16_cvt(h_);
            }
        }
        __syncthreads();
        // ---------- body B: s = 2*s2+1 (read zz[1], write zz[0]) ----------
        if (w < NW1) {
            float xnew = 0.f;
            if (xr && s2 < T_LEN / 2 - 2) xnew = xp[0];   // x(2*s2+4)
            MFMA4(1, 2)
            GSC_XCHG(g_)
            GATES_MATH(g_, c1, h_)
            zz[0][offH] = bf16_cvt(h_);
            if (xr && s2 != T_LEN / 2 - 1)
                zz[0][xoff] = bf16_cvt(xv0);              // x(2*s2+2)
            xv0 = xv1; xv1 = xnew; xp += IN_F;
        } else {
            MFMA4(1, 3)
            GSC_XCHG(g_)
            GATES_MATH(g_, c2, h_)
            zz[0][off2j] = bf16_cvt(h_);
        }
        __syncthreads();
    }

    // ================= epilogue: layer2 step T-1 (zz[0]: h1(511), h2(510)) ====
    if (w >= NW1) {
        MFMA4(0, 3)
        GSC_XCHG(g_)
        GATES_MATH(g_, c2, h_)
        h2f[b4 * H2 + u2j] = h_;
    }
    __syncthreads();

    // ================= FC head =================
    if (t < MB * FCN) {
        const int b = t >> 4, j = t & 15;
        float s1 = fc1_b[j];
        #pragma unroll
        for (int k = 0; k < H2; ++k)
            s1 = fmaf(fc1_w[j * H2 + k], h2f[b * H2 + k], s1);
        fcs[b * FCN + j] = fmaxf(s1, 0.f);
    }
    __syncthreads();
    if (t < MB) {
        float s2v = fc2_b[0];
        #pragma unroll
        for (int j = 0; j < FCN; ++j)
            s2v = fmaf(fc2_w[j], fcs[t * FCN + j], s2v);
        out[b0 + t] = s2v;
    }
}

extern "C" void kernel_launch(void* const* d_in, const int* in_sizes, int n_in,
                              void* d_out, int out_size, void* d_ws, size_t ws_size,
                              hipStream_t stream) {
    const float* x     = (const float*)d_in[0];
    const float* Wih1  = (const float*)d_in[1];
    const float* Whh1  = (const float*)d_in[2];
    const float* bih1  = (const float*)d_in[3];
    const float* bhh1  = (const float*)d_in[4];
    const float* Wih2  = (const float*)d_in[5];
    const float* Whh2  = (const float*)d_in[6];
    const float* bih2  = (const float*)d_in[7];
    const float* bhh2  = (const float*)d_in[8];
    const float* fc1_w = (const float*)d_in[9];
    const float* fc1_b = (const float*)d_in[10];
    const float* fc2_w = (const float*)d_in[11];
    const float* fc2_b = (const float*)d_in[12];
    float* out = (float*)d_out;

    const int n_batch = 2048;
    dim3 grid(n_batch / MB), block(BLK);
    lstm_mfma<<<grid, block, 0, stream>>>(x, Wih1, Whh1, bih1, bhh1,
                                          Wih2, Whh2, bih2, bhh2,
                                          fc1_w, fc1_b, fc2_w, fc2_b, out);
}

// Round 11
// 306.856 us; speedup vs baseline: 1.9444x; 1.9444x over previous
//
#include <hip/hip_runtime.h>

// LSTMTrafficPredictor: fused 2-layer LSTM + FC head via MFMA.
// B=2048, T=512, IN=4, H1=64, H2=32, FC=16, OUT=1.
//
// R28 = R25 champion (261.0us) + merged single-rcp gate math (ONLY change).
// R26/R27 post-mortem: 2-blocks/CU CATASTROPHIC (557us): Occupancy 17.5% =
// one 6-wave block/CU -> blocks NEVER co-resided (512 blocks ran as two
// sequential passes, 2x278us); gsc b128 read was also 8-way bank-conflicted
// (14K -> 9.4M). Axis measured-closed: 64-AGPR-pin waves deny 2-block
// co-residency on this scheduler. Exchange stays SWZ8.
// R28 theory: trans pipe is the dominant issue consumer (384 of 610
// cy/SIMD/body = measured VALUBusy 60%). Gate math used 5 exp + 3 rcp;
// the two sigmoid-pair rcps merge into ONE: r = rcp(P12*P34), Q1 = P34*r
// (=1/P12), Q2 = P12*r (=1/P34). +3 muls (6cy VALU), -1 rcp (16cy trans)
// per lane-job -> trans 384->336 cy/SIMD/body. Overflow-safe: |gate|<~10
// -> product <~1e17 << f32 max.
// PRE-COMMITMENT: if flat/regressed, declare the structural floor (every
// fill mechanism for the ~40% chain-latency idle is measured-closed).
// CLOSED AXES (measured): issue-trimming of regular VALU (R19 flat), VALU
// x-fold (R20 -6%), dup-column stores (R22 -3%), MFMA chain-split (R24
// -16%), x-prefetch depth>2 (R25 flat = kept), 2 blocks/CU (R26 -113%),
// MB=16 (half CUs), finer wave split, batch-group phase split (MFMA cols),
// cross-wave ACT2 redistribution (R16).
// Structure: BLK=768 (12 waves: 8 L1 + 4 L2), grid=256, bounds(768,3),
// AGPR-pinned frags, unroll-2 ping-pong, 1 barrier/body, exp2-folded
// weights, ds_swizzle xor-8 redistribution, x-prefetch depth 2.
// k-map (K=128): [h1(0..63) | x(64..67) | 0(68..95) | h2(96..127)]
//   L1: 2 tiles/wave w<8 (unit w*8+nt*4+quad), ks {0,1,2}, C-init=bb1 (AGPR)
//   L2: 2 tiles/wave w>=8 (unit (w-8)*8+tt*4+quad), ks {0,1,3}, C-init=bb2
//   z offset(k,n) = (k>>5)*512 + (((k>>3)&3)*16+n)*8 + (k&7); frag read = lane*8.
// ACT job map (both layers): lane(quad,col) -> unit base + (col>>3)*4 + quad,
//   batch col&7; col<8 uses own acc tile0, col>=8 uses swizzle(xor8) tile1.

#define T_LEN 512
#define IN_F  4
#define H1    64
#define H2    32
#define FCN   16
#define MB    8
#define BLK   768
#define NW1   8     // layer-1 waves; waves NW1..11 are layer-2

typedef __attribute__((ext_vector_type(8))) short s8b;  // 8 bf16 = 4 VGPR
typedef __attribute__((ext_vector_type(4))) float f4;   // MFMA acc
typedef __attribute__((ext_vector_type(4))) int   i4;   // 4 dwords (pin unit)

union S8U { s8b v; i4 d; unsigned short u[8]; };
union F4U { f4 v; i4 d; float f[4]; };

// Pin 4 consecutive regs into AGPRs; asm def kills rematerialization.
#define APIN4(x) asm volatile("" : "+a"((x).d))

#define MF(a, b, c) __builtin_amdgcn_mfma_f32_16x16x32_bf16((a), (b), (c), 0, 0, 0)
#define EX2(x) __builtin_amdgcn_exp2f(x)

#define L2E   1.4426950408889634f
#define L2E2  2.885390081777927f   // 2*log2(e)

__device__ __forceinline__ float rcp_(float x) { return __builtin_amdgcn_rcpf(x); }
// tanh(x) via exp2: 1 - 2/(2^(2x*log2e)+1)
__device__ __forceinline__ float tanh_(float x) {
    return 1.0f - 2.0f * rcp_(EX2(x * L2E2) + 1.0f);
}

__device__ __forceinline__ unsigned short bf16_rne(float f) {   // loader only
    unsigned u = __float_as_uint(f);
    u = u + 0x7FFFu + ((u >> 16) & 1u);
    return (unsigned short)(u >> 16);
}
__device__ __forceinline__ unsigned short bf16_cvt(float f) {   // hot path: 1 instr
    unsigned r;
    asm("v_cvt_pk_bf16_f32 %0, %1, %2" : "=v"(r) : "v"(f), "v"(f));
    return (unsigned short)r;
}

// xor-8 lane swizzle of an f4 (4x ds_swizzle_b32, BitMode xor=8)
#define SWZ8(dst, src)                                                          \
    { F4U t_; t_.v = (src);                                                     \
      (dst).d[0] = __builtin_amdgcn_ds_swizzle(t_.d[0], 0x201F);                \
      (dst).d[1] = __builtin_amdgcn_ds_swizzle(t_.d[1], 0x201F);                \
      (dst).d[2] = __builtin_amdgcn_ds_swizzle(t_.d[2], 0x201F);                \
      (dst).d[3] = __builtin_amdgcn_ds_swizzle(t_.d[3], 0x201F); }

// Merged single-rcp gate math (gates pre-scaled: i,f,o by log2e; g by
// 2*log2e). One rcp serves both sigmoid pairs: Q1 = 1/(dI*dF), Q2 =
// 1/(dG*dO) via r = rcp(P12*P34). 5 exp + 2 rcp (+ tanh's inside).
#define GATES_MATH(G_, CREG, HOUT)                                              \
    const float dI = 1.0f + EX2(-(G_)[0]);                                      \
    const float dF = 1.0f + EX2(-(G_)[1]);                                      \
    const float dG = EX2((G_)[2]) + 1.0f;                                       \
    const float dO = 1.0f + EX2(-(G_)[3]);                                      \
    const float P12 = dI * dF, P34 = dG * dO;                                   \
    const float r_ = rcp_(P12 * P34);                                           \
    const float Q1 = P34 * r_, Q2 = P12 * r_;                                   \
    const float I = dF * Q1, F = dI * Q1;                                       \
    const float O = dG * Q2, t_g = dO * Q2;                                     \
    const float Gg = fmaf(-2.0f, t_g, 1.0f);                                    \
    CREG = fmaf(F, CREG, I * Gg);                                               \
    const float HOUT = O * tanh_(CREG);

// ---- layer-1 core (waves 0..7): 6 MFMA (serial chains), swizzle redist,
// ACT1, h1 store. x staging handled by the caller (prefetch pipeline). ----
#define L1_CORE(P, NP)                                                          \
    {                                                                           \
        const s8b z0 = *(const s8b*)(&zz[P][0] + 0 * 512 + offF);               \
        const s8b z1 = *(const s8b*)(&zz[P][0] + 1 * 512 + offF);               \
        const s8b z2 = *(const s8b*)(&zz[P][0] + 2 * 512 + offF);               \
        f4 a0 = MF(wf1[0][0].v, z0, bb1[0].v);                                  \
        f4 a1 = MF(wf1[1][0].v, z0, bb1[1].v);                                  \
        a0 = MF(wf1[0][1].v, z1, a0);                                           \
        a1 = MF(wf1[1][1].v, z1, a1);                                           \
        a0 = MF(wf1[0][2].v, z2, a0);                                           \
        a1 = MF(wf1[1][2].v, z2, a1);                                           \
        F4U rsw; SWZ8(rsw, a1)                                                  \
        f4 g_;                                                                  \
        _Pragma("unroll")                                                       \
        for (int j_ = 0; j_ < 4; ++j_) g_[j_] = lowc ? a0[j_] : rsw.f[j_];      \
        GATES_MATH(g_, c1, h_)                                                  \
        zz[NP][offH] = bf16_cvt(h_);                                            \
    }

// ---- layer-2 body (waves 8..11): 6 MFMA (serial chains), swizzle redist,
// ACT2 (lagged step), h2 store ----
#define L2_MFMA(P)                                                              \
    f4 q0, q1;                                                                  \
    {                                                                           \
        const s8b z0 = *(const s8b*)(&zz[P][0] + 0 * 512 + offF);               \
        const s8b z1 = *(const s8b*)(&zz[P][0] + 1 * 512 + offF);               \
        const s8b z3 = *(const s8b*)(&zz[P][0] + 3 * 512 + offF);               \
        q0 = MF(wf2[0][0].v, z0, bb2[0].v);                                     \
        q1 = MF(wf2[1][0].v, z0, bb2[1].v);                                     \
        q0 = MF(wf2[0][1].v, z1, q0);                                           \
        q1 = MF(wf2[1][1].v, z1, q1);                                           \
        q0 = MF(wf2[0][2].v, z3, q0);                                           \
        q1 = MF(wf2[1][2].v, z3, q1);                                           \
    }

#define L2_ACT(NP)                                                              \
    {                                                                           \
        F4U rsw; SWZ8(rsw, q1)                                                  \
        f4 g_;                                                                  \
        _Pragma("unroll")                                                       \
        for (int j_ = 0; j_ < 4; ++j_) g_[j_] = lowc ? q0[j_] : rsw.f[j_];      \
        GATES_MATH(g_, c2, h_)                                                  \
        zz[NP][off2j] = bf16_cvt(h_);                                           \
    }

__global__ __launch_bounds__(BLK, 3)
void lstm_mfma(const float* __restrict__ x,
               const float* __restrict__ Wih1, const float* __restrict__ Whh1,
               const float* __restrict__ bih1, const float* __restrict__ bhh1,
               const float* __restrict__ Wih2, const float* __restrict__ Whh2,
               const float* __restrict__ bih2, const float* __restrict__ bhh2,
               const float* __restrict__ fc1_w, const float* __restrict__ fc1_b,
               const float* __restrict__ fc2_w, const float* __restrict__ fc2_b,
               float* __restrict__ out)
{
    __shared__ __align__(16) unsigned short zz[2][2048];     // 8 KB
    __shared__ __align__(16) float h2f[MB * H2];
    __shared__ __align__(16) float fcs[MB * FCN];

    const int t    = threadIdx.x;
    const int lane = t & 63;
    const int w    = t >> 6;      // wave 0..11
    const int col  = lane & 15;
    const int quad = lane >> 4;
    const int b0   = blockIdx.x * MB;
    const bool lowc = (col < 8);
    const int w2   = (w >= NW1) ? (w - NW1) : 0;   // L2 wave idx (clamped)

    // ---- weight fragments (bf16, exp2-folded: g-gate rows x 2*log2e) ----
    const float wsc = ((col & 3) == 2) ? L2E2 : L2E;
    S8U wf1[2][3];                // layer1: 2 tiles x ks {0,1,2}
    S8U wf2[2][3];                // layer2: 2 tiles x ks {0,1,3}
    #pragma unroll
    for (int nt = 0; nt < 2; ++nt) {
        const int r1u = (col & 3) * 64 + (w < NW1 ? w : 0) * 8 + nt * 4 + (col >> 2);
        #pragma unroll
        for (int ks = 0; ks < 3; ++ks) {
            #pragma unroll
            for (int j = 0; j < 8; ++j) {
                const int k = ks * 32 + quad * 8 + j;
                float wv = 0.f;
                if      (k < H1)           wv = Whh1[r1u * H1 + k];
                else if (k < H1 + IN_F)    wv = Wih1[r1u * IN_F + (k - H1)];
                wf1[nt][ks].u[j] = bf16_rne(wv * wsc);
            }
        }
    }
    #pragma unroll
    for (int tt = 0; tt < 2; ++tt) {
        const int r2 = (col & 3) * 32 + w2 * 8 + tt * 4 + (col >> 2);
        #pragma unroll
        for (int kf = 0; kf < 3; ++kf) {
            #pragma unroll
            for (int j = 0; j < 8; ++j) {
                const int k = ((kf < 2) ? kf * 32 : 96) + quad * 8 + j;
                const float wv = (k < H1) ? Wih2[r2 * H1 + k]
                                          : Whh2[r2 * H2 + (k - 96)];
                wf2[tt][kf].u[j] = bf16_rne(wv * wsc);
            }
        }
    }
    // biases as exact-f32 MFMA C-init (pre-scaled)
    F4U bb1[2], bb2[2];
    #pragma unroll
    for (int j = 0; j < 4; ++j) {
        const float bsc = (j == 2) ? L2E2 : L2E;
        const int u1a = (w < NW1 ? w : 0) * 8 + quad;         // nt=0 unit
        const int u1b = u1a + 4;                              // nt=1 unit
        bb1[0].f[j] = (bih1[j * 64 + u1a] + bhh1[j * 64 + u1a]) * bsc;
        bb1[1].f[j] = (bih1[j * 64 + u1b] + bhh1[j * 64 + u1b]) * bsc;
        const int u2a = w2 * 8 + quad;                        // tt=0 unit
        const int u2b = u2a + 4;                              // tt=1 unit
        bb2[0].f[j] = (bih2[j * 32 + u2a] + bhh2[j * 32 + u2a]) * bsc;
        bb2[1].f[j] = (bih2[j * 32 + u2b] + bhh2[j * 32 + u2b]) * bsc;
    }

    // ---- PIN fragments + biases into AGPRs ----
    #pragma unroll
    for (int nt = 0; nt < 2; ++nt)
        #pragma unroll
        for (int ks = 0; ks < 3; ++ks) { APIN4(wf1[nt][ks]); APIN4(wf2[nt][ks]); }
    APIN4(bb1[0]); APIN4(bb1[1]); APIN4(bb2[0]); APIN4(bb2[1]);

    // ---- init LDS: zero z (both buffers) ----
    {
        int* pz = (int*)zz;       // 2*2048 shorts = 2048 ints
        for (int i = t; i < 2048; i += BLK) pz[i] = 0;
    }
    __syncthreads();
    if (t < MB * IN_F) {                    // x(0) at k=64+f: off = 1024 + n*8 + f
        const int n = t >> 2, f = t & 3;
        const float xv = x[(size_t)(b0 + n) * T_LEN * IN_F + f];
        zz[0][1024 + n * 8 + f] = bf16_rne(xv);
    }
    float c1 = 0.f;   // L1 job: unit w*8+(col>>3)*4+quad, batch col&7
    float c2 = 0.f;   // L2 job: unit w2*8+(col>>3)*4+quad, batch col&7

    // store offsets
    const int uH    = w * 8 + ((col >> 3) << 2) + quad;            // L1 (w<8)
    const int nH    = col & 7;
    const int offH  = (uH >> 5) * 512 + (((uH >> 3) & 3) * 16 + nH) * 8 + (uH & 7);
    const int u2j   = w2 * 8 + ((col >> 3) << 2) + quad;           // L2 (w>=8)
    const int off2j = 1536 + (((u2j >> 3) & 3) * 16 + nH) * 8 + (u2j & 7);
    const int offF  = lane * 8;                    // frag read base
    const int xn_   = (t >> 2) & 7, xf_ = t & 3;   // x-prefetch role (t < 32)
    const int xoff  = 1024 + xn_ * 8 + xf_;
    const bool xr   = (t < MB * IN_F);
    const float* xp = x + (size_t)(b0 + xn_) * T_LEN * IN_F + IN_F + xf_;  // -> x(1)

    // x prefetch pipeline, depth 2: loads land >= 2 bodies before cvt+store.
    float xv0 = 0.f, xv1 = 0.f;
    if (xr) {
        xv0 = xp[0];          // x(1)
        xv1 = xp[IN_F];       // x(2)
        xp += 2 * IN_F;       // -> x(3)
    }
    __syncthreads();

    // ================= main recurrence: unrolled x2, 1 barrier/body ==========
    #pragma unroll 1
    for (int s2 = 0; s2 < T_LEN / 2; ++s2) {
        // ---------- body A: s = 2*s2 (read zz[0], write zz[1]) ----------
        if (w < NW1) {
            float xnew = 0.f;
            if (xr && s2 < T_LEN / 2 - 1) xnew = xp[0];   // x(2*s2+3)
            L1_CORE(0, 1)
            if (xr) zz[1][xoff] = bf16_cvt(xv0);          // x(2*s2+1), 2-body-old
            xv0 = xv1; xv1 = xnew; xp += IN_F;
        } else {
            L2_MFMA(0)
            if (s2 != 0) L2_ACT(1)       // first body: h2(-1) must stay 0
        }
        __syncthreads();
        // ---------- body B: s = 2*s2+1 (read zz[1], write zz[0]) ----------
        if (w < NW1) {
            float xnew = 0.f;
            if (xr && s2 < T_LEN / 2 - 2) xnew = xp[0];   // x(2*s2+4)
            L1_CORE(1, 0)
            if (xr && s2 != T_LEN / 2 - 1)
                zz[0][xoff] = bf16_cvt(xv0);              // x(2*s2+2)
            xv0 = xv1; xv1 = xnew; xp += IN_F;
        } else {
            L2_MFMA(1)
            L2_ACT(0)
        }
        __syncthreads();
    }

    // ================= epilogue: layer2 step T-1 (zz[0]: h1(511), h2(510)) ====
    if (w >= NW1) {
        L2_MFMA(0)
        {
            F4U rsw; SWZ8(rsw, q1)
            f4 g_;
            #pragma unroll
            for (int j_ = 0; j_ < 4; ++j_) g_[j_] = lowc ? q0[j_] : rsw.f[j_];
            GATES_MATH(g_, c2, h_)
            h2f[nH * H2 + u2j] = h_;
        }
    }
    __syncthreads();

    // ================= FC head =================
    if (t < MB * FCN) {
        const int b = t >> 4, j = t & 15;
        float s1 = fc1_b[j];
        #pragma unroll
        for (int k = 0; k < H2; ++k)
            s1 = fmaf(fc1_w[j * H2 + k], h2f[b * H2 + k], s1);
        fcs[b * FCN + j] = fmaxf(s1, 0.f);
    }
    __syncthreads();
    if (t < MB) {
        float s2v = fc2_b[0];
        #pragma unroll
        for (int j = 0; j < FCN; ++j)
            s2v = fmaf(fc2_w[j], fcs[t * FCN + j], s2v);
        out[b0 + t] = s2v;
    }
}

extern "C" void kernel_launch(void* const* d_in, const int* in_sizes, int n_in,
                              void* d_out, int out_size, void* d_ws, size_t ws_size,
                              hipStream_t stream) {
    const float* x     = (const float*)d_in[0];
    const float* Wih1  = (const float*)d_in[1];
    const float* Whh1  = (const float*)d_in[2];
    const float* bih1  = (const float*)d_in[3];
    const float* bhh1  = (const float*)d_in[4];
    const float* Wih2  = (const float*)d_in[5];
    const float* Whh2  = (const float*)d_in[6];
    const float* bih2  = (const float*)d_in[7];
    const float* bhh2  = (const float*)d_in[8];
    const float* fc1_w = (const float*)d_in[9];
    const float* fc1_b = (const float*)d_in[10];
    const float* fc2_w = (const float*)d_in[11];
    const float* fc2_b = (const float*)d_in[12];
    float* out = (float*)d_out;

    const int n_batch = 2048;
    dim3 grid(n_batch / MB), block(BLK);
    lstm_mfma<<<grid, block, 0, stream>>>(x, Wih1, Whh1, bih1, bhh1,
                                          Wih2, Whh2, bih2, bhh2,
                                          fc1_w, fc1_b, fc2_w, fc2_b, out);
}